// Round 7
// baseline (345.631 us; speedup 1.0000x reference)
//
#include <hip/hip_runtime.h>
#include <math.h>

// Problem constants (B, C, H, W) = (32, 10, 192, 320), fp32.
constexpr int B_ = 32, C_ = 10, H_ = 192, W_ = 320;
constexpr int HW_  = H_ * W_;        // 61440 (512 | HW_ -> no b-crossing per block)
constexpr int CHW_ = C_ * HW_;       // 614400
constexpr int NPTS = B_ * HW_;       // 1966080 spatial points
constexpr int PPT  = 2;              // points per thread (float2 loads) -- R0 proven shape
constexpr int TPB  = 256;
constexpr int NTHR = NPTS / PPT;     // 983040
constexpr int NBLK = NTHR / TPB;     // 3840 blocks, exact cover

// Partial-sum slots, ws[slot * NBLK + blk]; counter at ws + NACC*NBLK.
// 0: nv  1: num_pos
// 2: sum pos*(g0-r0)^2*log(safe+EPS)            (pos_term = -this)
// 3: sum neg*r0^2*log(1+EPS-safe)*(1-g0)^4      (neg_term = -this)
// 4: P  = 0.5*s_pos + 0.5*s_const + 0.1*s_h     (-> P/nv)
// 5: V1 = 0.05*s_len1 + 0.5*s_trig1             (-> V1/nv)
// 6: V2 = 0.05*s_len2 + 0.5*s_trig2             (-> V2/nv)
// loss = focal + (P + min(V1,V2)) / nv
#define NACC 7

typedef float f32x2 __attribute__((ext_vector_type(2)));

__device__ __forceinline__ float sl1f(float d) {
    float ad = fabsf(d);
    return ad < 1.0f ? 0.5f * d * d : ad - 0.5f;
}

// Round-10 design. Closed questions:
//   - nt loads: 3.4x REGRESSION with unchanged FETCH_SIZE (R6) -> reverted.
//   - MLP depth: R0 (MLP~2, 19 w/CU), R3 (verified 20-deep LDS), R5
//     (verified loop-carried pipeline) all deliver 4.3 B/cyc/CU ->
//     per-CU outstanding-fill cap; software queue depth is irrelevant.
//     Main loop is at its ceiling (~84% of best demonstrated read rate).
// This round keeps the R0-proven main body and banks the last clean win:
// fused last-block reduce with a MODULO counter -- old%NBLK==NBLK-1 marks
// the last arrival of each launch regardless of initial counter value, so
// NO memset dispatch is needed (correct across graph replays, and whether
// or not the harness zeroes d_ws). Kills one dispatch + inter-kernel gap.
__global__ __launch_bounds__(TPB) void loss_fused(
    const float* __restrict__ re, const float* __restrict__ gt,
    float* __restrict__ ws, unsigned int* __restrict__ cnt,
    float* __restrict__ out)
{
    const int tid = blockIdx.x * TPB + threadIdx.x;
    const int p = tid * PPT;
    const int b = p / HW_;           // no b-crossing (PPT*TPB=512 divides HW_)
    const int s = p - b * HW_;
    const float* rp = re + (size_t)b * CHW_ + s;
    const float* gp = gt + (size_t)b * CHW_ + s;

    // 20 coalesced dwordx2 loads (plain: L1/L2/L3 all in play -- R0 form).
    f32x2 R[10], G[10];
#pragma unroll
    for (int c = 0; c < 10; ++c) {
        R[c] = *(const f32x2*)(rp + c * HW_);
        G[c] = *(const f32x2*)(gp + c * HW_);
    }

    float acc[NACC];
#pragma unroll
    for (int i = 0; i < NACC; ++i) acc[i] = 0.0f;

#pragma unroll
    for (int j = 0; j < PPT; ++j) {
        const float g = G[0][j], r = R[0][j];
        const float m = (g == 1.0f) ? 1.0f : 0.0f;
        acc[0] += m;
        const float pos = (g >= 0.1f) ? 1.0f : 0.0f;
        const float neg = ((g >= 0.0f) && (g < 0.1f)) ? 1.0f : 0.0f;
        acc[1] += pos;
        const float safe = fminf(fmaxf(r, 1e-6f), 1.0f - 1e-6f);
        // pos and neg mutually exclusive -> one logf with selected argument.
        const float larg = (pos != 0.0f) ? (safe + 6e-8f)
                                         : (1.0f + 6e-8f - safe);
        const float lg = logf(larg);
        const float d0 = g - r;
        acc[2] += pos * (d0 * d0) * lg;
        const float omg = 1.0f - g;
        const float omg2 = omg * omg;
        acc[3] += neg * (r * r) * (omg2 * omg2) * lg;

        const float r1 = R[1][j], r2 = R[2][j], r3 = R[3][j], r4v = R[4][j];
        const float r5 = R[5][j], r6 = R[6][j], r7 = R[7][j], r8 = R[8][j],
                    r9 = R[9][j];
        const float g1 = G[1][j], g2 = G[2][j], g3 = G[3][j], g4v = G[4][j];
        const float g5 = G[5][j], g6 = G[6][j], g7 = G[7][j], g8 = G[8][j],
                    g9 = G[9][j];

        // P: pos(0.5) + const(0.5) + height(0.1), all later /nv
        const float sp = sl1f(r1 - g1) + sl1f(r2 - g2);
        const float c1 = 1.0f - r5 * r5 - r4v * r4v;
        const float c2 = 1.0f - r8 * r8 - r7 * r7;
        const float sc = c1 * c1 + c2 * c2;
        const float sh = sl1f(r9 - g9);
        acc[4] += m * (0.5f * sp + 0.5f * sc + 0.1f * sh);

        // V1: 0.05*len1 + 0.5*trig1
        const float d44 = r4v - g4v, d77 = r7 - g7;
        const float d55 = r5 - g5,  d88 = r8 - g8;
        const float t1 = d44 * d44 + d77 * d77 + d55 * d55 + d88 * d88;
        const float l1 = sl1f(r3 - g3) + sl1f(r6 - g6);
        acc[5] += m * (0.05f * l1 + 0.5f * t1);

        // V2: 0.05*len2 + 0.5*trig2
        const float d47 = r4v - g7, d74 = r7 - g4v;
        const float d58 = r5 - g8,  d85 = r8 - g5;
        const float t2 = d47 * d47 + d74 * d74 + d58 * d58 + d85 * d85;
        const float l2 = sl1f(r3 - g6) + sl1f(r6 - g3);
        acc[6] += m * (0.05f * l2 + 0.5f * t2);
    }

    // block reduction: wave shuffle (64 lanes) -> LDS (4 waves)
    __shared__ float smem[NACC][4];
    const int lane = threadIdx.x & 63;
    const int wid  = threadIdx.x >> 6;
#pragma unroll
    for (int i = 0; i < NACC; ++i) {
        float v = acc[i];
#pragma unroll
        for (int off = 32; off > 0; off >>= 1) v += __shfl_down(v, off, 64);
        if (lane == 0) smem[i][wid] = v;
    }
    __syncthreads();

    // thread 0 stores ALL 7 partials (one thread's release fence orders them
    // all), then signals completion. Modulo test: last arrival of THIS launch
    // regardless of the counter's starting value -> no reset dispatch needed.
    __shared__ int isLast;
    if (threadIdx.x == 0) {
#pragma unroll
        for (int i = 0; i < NACC; ++i)
            ws[i * NBLK + blockIdx.x] =
                smem[i][0] + smem[i][1] + smem[i][2] + smem[i][3];
        __threadfence();                                   // release
        const unsigned old = atomicAdd(cnt, 1u);           // device-scope
        isLast = ((old % (unsigned)NBLK) == (unsigned)(NBLK - 1));
    }
    __syncthreads();
    if (!isLast) return;

    // ---- last block only: final reduction of 7 x 3840 partials ----
    __threadfence();                                       // acquire
    float a2[NACC];
#pragma unroll
    for (int i = 0; i < NACC; ++i) a2[i] = 0.0f;
#pragma unroll
    for (int k = 0; k < NBLK / TPB; ++k) {                 // 15 iterations
        const int idx = threadIdx.x + k * TPB;
#pragma unroll
        for (int i = 0; i < NACC; ++i)
            a2[i] += ws[i * NBLK + idx];
    }
#pragma unroll
    for (int i = 0; i < NACC; ++i) {
        float v = a2[i];
#pragma unroll
        for (int off = 32; off > 0; off >>= 1) v += __shfl_down(v, off, 64);
        if (lane == 0) smem[i][wid] = v;
    }
    __syncthreads();

    if (threadIdx.x == 0) {
        float slot[NACC];
#pragma unroll
        for (int i = 0; i < NACC; ++i)
            slot[i] = smem[i][0] + smem[i][1] + smem[i][2] + smem[i][3];
        const float nv    = slot[0];
        const float npos  = slot[1];
        const float pterm = -slot[2];
        const float nterm = -slot[3];
        const float focal = (npos == 0.0f) ? nterm : (pterm + nterm) / npos;
        out[0] = focal + (slot[4] + fminf(slot[5], slot[6])) / nv;
    }
}

extern "C" void kernel_launch(void* const* d_in, const int* in_sizes, int n_in,
                              void* d_out, int out_size, void* d_ws, size_t ws_size,
                              hipStream_t stream)
{
    const float* re = (const float*)d_in[0];
    const float* gt = (const float*)d_in[1];
    float* ws  = (float*)d_ws;
    unsigned int* cnt = (unsigned int*)(ws + NACC * NBLK);
    float* out = (float*)d_out;

    loss_fused<<<NBLK, TPB, 0, stream>>>(re, gt, ws, cnt, out);
}

// Round 8
// 172.624 us; speedup vs baseline: 2.0022x; 2.0022x over previous
//
#include <hip/hip_runtime.h>
#include <math.h>

// Problem constants (B, C, H, W) = (32, 10, 192, 320), fp32.
constexpr int B_ = 32, C_ = 10, H_ = 192, W_ = 320;
constexpr int HW_  = H_ * W_;        // 61440 (divisible by 2)
constexpr int CHW_ = C_ * HW_;       // 614400
constexpr int NPTS = B_ * HW_;       // 1966080 spatial points
constexpr int PPT  = 2;              // points per thread
constexpr int NTHR = NPTS / PPT;     // 983040 threads
constexpr int NBLK = NTHR / 256;     // 3840 blocks, exact cover

// Partial-sum slots, ws[slot * NBLK + blk]. Final weights are folded into
// per-thread accumulation so only 7 slots survive:
// 0: nv      (sum of valid mask)
// 1: num_pos
// 2: sum pos*(g0-r0)^2*log(safe+EPS)            (pos_term = -this)
// 3: sum neg*r0^2*log(1+EPS-safe)*(1-g0)^4      (neg_term = -this)
// 4: P  = 0.5*s_pos + 0.5*s_const + 0.1*s_h     (-> P/nv)
// 5: V1 = 0.05*s_len1 + 0.5*s_trig1             (-> V1/nv)
// 6: V2 = 0.05*s_len2 + 0.5*s_trig2             (-> V2/nv)
// loss = focal + (P + min(V1,V2)) / nv
#define NACC 7

__device__ __forceinline__ float sl1f(float d) {
    float ad = fabsf(d);
    return ad < 1.0f ? 0.5f * d * d : ad - 0.5f;
}

// Session summary (rounds 0-7): this baseline's 59.5 us main loop is at a
// per-CU outstanding-fill service cap (~4.3 B/cyc/CU, 84% of the best
// demonstrated read rate). Falsified alternatives, each verified by counter
// structure: deep register epoch (compiler sinks loads; 3 attempts), LDS
// staging w/ 20 loads in flight (R3: same 59.5us), loop-carried software
// pipeline at 92 VGPR (R5: 63us, pipeline overhead), non-temporal loads
// (R6: slow path, 3.4x), fused last-block reduce (R7: per-block
// __threadfence = per-XCD L2 writeback/invalidate on gfx950 -> TCC stalls,
// delivered BW 2.64 -> 0.67 TB/s). This file is the verbatim best kernel.
__global__ __launch_bounds__(256) void loss_main(
    const float* __restrict__ re, const float* __restrict__ gt,
    float* __restrict__ ws)
{
    const int tid = blockIdx.x * 256 + threadIdx.x;
    const int p = tid * PPT;
    const int b = p / HW_;
    const int s = p - b * HW_;
    const float* rp = re + (size_t)b * CHW_ + s;
    const float* gp = gt + (size_t)b * CHW_ + s;

    // One load epoch: 20 independent coalesced dwordx2 loads.
    float2 R[10], G[10];
#pragma unroll
    for (int c = 0; c < 10; ++c) {
        R[c] = *(const float2*)(rp + c * HW_);
        G[c] = *(const float2*)(gp + c * HW_);
    }

    float acc[NACC];
#pragma unroll
    for (int i = 0; i < NACC; ++i) acc[i] = 0.0f;

#pragma unroll
    for (int j = 0; j < PPT; ++j) {
        #define RC(c) (((const float*)&R[c])[j])
        #define GC(c) (((const float*)&G[c])[j])
        const float g = GC(0), r = RC(0);
        const float m = (g == 1.0f) ? 1.0f : 0.0f;
        acc[0] += m;
        const float pos = (g >= 0.1f) ? 1.0f : 0.0f;
        const float neg = ((g >= 0.0f) && (g < 0.1f)) ? 1.0f : 0.0f;
        acc[1] += pos;
        const float safe = fminf(fmaxf(r, 1e-6f), 1.0f - 1e-6f);
        const float d0 = g - r;
        acc[2] += pos * (d0 * d0) * logf(safe + 6e-8f);
        const float omg = 1.0f - g;
        const float omg2 = omg * omg;
        acc[3] += neg * (r * r) * logf(1.0f + 6e-8f - safe) * (omg2 * omg2);

        const float r1 = RC(1), r2 = RC(2), r3 = RC(3), r4v = RC(4);
        const float r5 = RC(5), r6 = RC(6), r7 = RC(7), r8 = RC(8), r9 = RC(9);
        const float g1 = GC(1), g2 = GC(2), g3 = GC(3), g4v = GC(4);
        const float g5 = GC(5), g6 = GC(6), g7 = GC(7), g8 = GC(8), g9 = GC(9);

        // P: pos(0.5) + const(0.5) + height(0.1), all later /nv
        const float sp = sl1f(r1 - g1) + sl1f(r2 - g2);
        const float c1 = 1.0f - r5 * r5 - r4v * r4v;
        const float c2 = 1.0f - r8 * r8 - r7 * r7;
        const float sc = c1 * c1 + c2 * c2;
        const float sh = sl1f(r9 - g9);
        acc[4] += m * (0.5f * sp + 0.5f * sc + 0.1f * sh);

        // V1: 0.05*len1 + 0.5*trig1
        const float d44 = r4v - g4v, d77 = r7 - g7;
        const float d55 = r5 - g5,  d88 = r8 - g8;
        const float t1 = d44 * d44 + d77 * d77 + d55 * d55 + d88 * d88;
        const float l1 = sl1f(r3 - g3) + sl1f(r6 - g6);
        acc[5] += m * (0.05f * l1 + 0.5f * t1);

        // V2: 0.05*len2 + 0.5*trig2
        const float d47 = r4v - g7, d74 = r7 - g4v;
        const float d58 = r5 - g8,  d85 = r8 - g5;
        const float t2 = d47 * d47 + d74 * d74 + d58 * d58 + d85 * d85;
        const float l2 = sl1f(r3 - g6) + sl1f(r6 - g3);
        acc[6] += m * (0.05f * l2 + 0.5f * t2);
        #undef RC
        #undef GC
    }

    // block reduction: wave shuffle (64 lanes) -> LDS (4 waves) -> plain store
    __shared__ float smem[NACC][4];
    const int lane = threadIdx.x & 63;
    const int wid  = threadIdx.x >> 6;
#pragma unroll
    for (int i = 0; i < NACC; ++i) {
        float v = acc[i];
#pragma unroll
        for (int off = 32; off > 0; off >>= 1) v += __shfl_down(v, off, 64);
        if (lane == 0) smem[i][wid] = v;
    }
    __syncthreads();
    if (threadIdx.x < NACC) {
        const int i = threadIdx.x;
        ws[i * NBLK + blockIdx.x] =
            smem[i][0] + smem[i][1] + smem[i][2] + smem[i][3];
    }
}

// One block, 1024 threads: all 7*3840 partials in one parallel load epoch.
__global__ __launch_bounds__(1024) void loss_reduce(
    const float* __restrict__ ws, float* __restrict__ out)
{
    constexpr int K = NBLK / 1024;   // 3.75 -> loop to 4 with bounds check
    float acc[NACC];
#pragma unroll
    for (int i = 0; i < NACC; ++i) acc[i] = 0.0f;

#pragma unroll
    for (int k = 0; k < 4; ++k) {
        const int idx = threadIdx.x + k * 1024;
        if (idx < NBLK) {
#pragma unroll
            for (int i = 0; i < NACC; ++i)
                acc[i] += ws[i * NBLK + idx];
        }
    }
    (void)K;

    __shared__ float smem[NACC][16];
    const int lane = threadIdx.x & 63;
    const int wid  = threadIdx.x >> 6;
#pragma unroll
    for (int i = 0; i < NACC; ++i) {
        float v = acc[i];
#pragma unroll
        for (int off = 32; off > 0; off >>= 1) v += __shfl_down(v, off, 64);
        if (lane == 0) smem[i][wid] = v;
    }
    __syncthreads();

    if (threadIdx.x == 0) {
        float slot[NACC];
#pragma unroll
        for (int i = 0; i < NACC; ++i) {
            float v = 0.0f;
#pragma unroll
            for (int w = 0; w < 16; ++w) v += smem[i][w];
            slot[i] = v;
        }
        const float nv    = slot[0];
        const float npos  = slot[1];
        const float pterm = -slot[2];
        const float nterm = -slot[3];
        const float focal = (npos == 0.0f) ? nterm : (pterm + nterm) / npos;
        out[0] = focal + (slot[4] + fminf(slot[5], slot[6])) / nv;
    }
}

extern "C" void kernel_launch(void* const* d_in, const int* in_sizes, int n_in,
                              void* d_out, int out_size, void* d_ws, size_t ws_size,
                              hipStream_t stream)
{
    const float* re = (const float*)d_in[0];
    const float* gt = (const float*)d_in[1];
    float* ws  = (float*)d_ws;
    float* out = (float*)d_out;

    loss_main<<<NBLK, 256, 0, stream>>>(re, gt, ws);
    loss_reduce<<<1, 1024, 0, stream>>>(ws, out);
}